// Round 15
// baseline (119.428 us; speedup 1.0000x reference)
//
#include <hip/hip_runtime.h>
#include <hip/hip_bf16.h>

#define NB 8
#define NC 128
#define NH 48
#define NW 64
#define NS 3072  // NH*NW
#define EPSF 1e-6f

#define GLOBAL_AS __attribute__((address_space(1)))
#define LDS_AS __attribute__((address_space(3)))

typedef __bf16 bf16x8 __attribute__((ext_vector_type(8)));
typedef float f32x4 __attribute__((ext_vector_type(4)));

__device__ __forceinline__ unsigned short bf16_rtne(float f) {
  union { float f; unsigned u; } c;
  c.f = f;
  unsigned r = (c.u + 0x7fffu + ((c.u >> 16) & 1u)) >> 16;
  return (unsigned short)r;
}

// ---------------------------------------------------------------------------
// Transpose+convert (vectorized, unchanged from round 10):
// f32 [B][C][S] -> bf16 [B][S][C].
// ---------------------------------------------------------------------------
__global__ __launch_bounds__(256) void transpose_both(
    const float* __restrict__ x, const float* __restrict__ y,
    __hip_bfloat16* __restrict__ AT, __hip_bfloat16* __restrict__ BT) {
  __shared__ float tile[32 * 129];  // 16,512 B
  const int id = blockIdx.x;
  const int b = id & 7;             // XCD pin
  const int which = (id >> 3) & 1;
  const int f0 = (id >> 4) * 32;    // 0..95 strips
  const float* src = which ? y : x;
  __hip_bfloat16* dst = which ? BT : AT;
  const int t = threadIdx.x;

  {  // phase 1: float4 reads, scatter-transpose to LDS
    const int fl = (t & 7) * 4, cg0 = t >> 3;
    const float* sp = src + (size_t)b * NC * NS + f0 + fl;
#pragma unroll
    for (int i = 0; i < 4; ++i) {
      int cg = cg0 + i * 32;
      f32x4 v = *(const f32x4*)(sp + (size_t)cg * NS);
      tile[(fl + 0) * 129 + cg] = v[0];
      tile[(fl + 1) * 129 + cg] = v[1];
      tile[(fl + 2) * 129 + cg] = v[2];
      tile[(fl + 3) * 129 + cg] = v[3];
    }
  }
  __syncthreads();
  {  // phase 2: row reads, RTNE pack, ushort4 stores
    const int c4 = (t & 31) * 4, kl0 = t >> 5;
    unsigned short* dp = (unsigned short*)dst;
#pragma unroll
    for (int i = 0; i < 4; ++i) {
      int fl = kl0 + i * 8;
      int f = f0 + fl;
      int k = which ? f : ((f & 63) * NH + (f >> 6));  // x: k = v*H + u
      f32x4 v = *(const f32x4*)&tile[fl * 129 + c4];
      ushort4 u4;
      u4.x = bf16_rtne(v[0]);
      u4.y = bf16_rtne(v[1]);
      u4.z = bf16_rtne(v[2]);
      u4.w = bf16_rtne(v[3]);
      *(ushort4*)(dp + ((size_t)b * NS + k) * NC + c4) = u4;
    }
  }
}

// ---------------------------------------------------------------------------
// Staging: CPW 1-KB chunks per wave; linear LDS dest, inverse-swizzled global
// source (verified round-1 pattern). Read side uses granule g ^ (row&7).
// ---------------------------------------------------------------------------
template <int CPW>
__device__ __forceinline__ void stage_tile(const char* gsrc, char* ldst,
                                           int wid, int lane) {
  const int lr = lane >> 4, lg = lane & 15;
#pragma unroll
  for (int i = 0; i < CPW; ++i) {
    int c = wid * CPW + i;
    int row = c * 4 + lr;
    int g = lg ^ (row & 7);
    __builtin_amdgcn_global_load_lds(
        (const GLOBAL_AS unsigned*)(gsrc + row * 256 + g * 16),
        (LDS_AS unsigned*)(ldst + c * 1024), 16, 0, 0);
  }
}

// ---------------------------------------------------------------------------
// Pass 1 v4: round-12 structure + B-fragments hoisted into registers
// (loop-invariant across the 3 A-tiles; cuts per-iter ds_reads in half).
// Grid 1536 = 8 b x 24 nt x 8 mg; 256 threads (4 waves, 2x2 of 64x64).
// part[mg][b][n] = sum over this block's 384 m-rows of relu(T)^2.
// ---------------------------------------------------------------------------
__global__ __launch_bounds__(256, 2) void corr_part_v4(
    const __hip_bfloat16* __restrict__ AT,
    const __hip_bfloat16* __restrict__ BT, float* __restrict__ part) {
  __shared__ char smem[65536];  // As 32K | Bs 32K
  char* As = smem;
  char* Bs = smem + 32768;
  const int id = blockIdx.x;  // 0..1535
  const int b = id & 7;       // XCD pin
  const int tl = id >> 3;     // 0..191
  const int nt = tl >> 3;     // 0..23
  const int mg = tl & 7;      // 0..7 (3 tiles of 128 rows each)
  const int t = threadIdx.x;
  const int lane = t & 63, wid = t >> 6;
  const int wm = wid >> 1, wn = wid & 1;
  const int l15 = lane & 15, kg = lane >> 4;

  const char* Ab = (const char*)(AT + ((size_t)b * NS + mg * 384) * NC);
  const char* Bg = (const char*)(BT + ((size_t)b * NS + nt * 128) * NC);

  stage_tile<8>(Bg, Bs, wid, lane);
  stage_tile<8>(Ab, As, wid, lane);  // tile 0
  asm volatile("s_waitcnt vmcnt(0)" ::: "memory");
  __builtin_amdgcn_sched_barrier(0);
  __builtin_amdgcn_s_barrier();

  // hoist all B fragments (loop-invariant): 16 x bf16x8 = 64 VGPR
  const int rx = l15 & 7;
  bf16x8 bfrag[4][4];
#pragma unroll
  for (int kk = 0; kk < 4; ++kk) {
    int g = (kk * 4 + kg) ^ rx;
#pragma unroll
    for (int ni = 0; ni < 4; ++ni)
      bfrag[kk][ni] =
          *(const bf16x8*)(Bs + (wn * 64 + ni * 16 + l15) * 256 + g * 16);
  }

  float cs[4] = {0.f, 0.f, 0.f, 0.f};
#pragma unroll 1
  for (int i = 0; i < 3; ++i) {
    f32x4 acc[4][4] = {};
#pragma unroll
    for (int kk = 0; kk < 4; ++kk) {
      int g = (kk * 4 + kg) ^ rx;
      bf16x8 a[4];
#pragma unroll
      for (int mi = 0; mi < 4; ++mi)
        a[mi] = *(const bf16x8*)(As + (wm * 64 + mi * 16 + l15) * 256 + g * 16);
#pragma unroll
      for (int mi = 0; mi < 4; ++mi)
#pragma unroll
        for (int ni = 0; ni < 4; ++ni)
          acc[mi][ni] = __builtin_amdgcn_mfma_f32_16x16x32_bf16(
              a[mi], bfrag[kk][ni], acc[mi][ni], 0, 0, 0);
    }
#pragma unroll
    for (int ni = 0; ni < 4; ++ni)
#pragma unroll
      for (int mi = 0; mi < 4; ++mi)
#pragma unroll
        for (int r = 0; r < 4; ++r) {
          float v = fmaxf(acc[mi][ni][r], 0.f);
          cs[ni] += v * v;
        }
    __builtin_amdgcn_s_barrier();  // all waves done reading As
    if (i + 1 < 3) {
      stage_tile<8>(Ab + (size_t)(i + 1) * 32768, As, wid, lane);
      asm volatile("s_waitcnt vmcnt(0)" ::: "memory");
      __builtin_amdgcn_sched_barrier(0);
      __builtin_amdgcn_s_barrier();
    }
  }

#pragma unroll
  for (int ni = 0; ni < 4; ++ni) {
    cs[ni] += __shfl_xor(cs[ni], 16, 64);
    cs[ni] += __shfl_xor(cs[ni], 32, 64);
  }
  float* csum = (float*)smem;  // [2][128]
  if (kg == 0) {
#pragma unroll
    for (int ni = 0; ni < 4; ++ni)
      csum[wm * 128 + wn * 64 + ni * 16 + l15] = cs[ni];
  }
  __syncthreads();
  if (t < 128) {
    float s = csum[t] + csum[128 + t];
    part[(size_t)mg * (NB * NS) + (size_t)b * NS + nt * 128 + t] = s;
  }
}

// ---------------------------------------------------------------------------
// Pass 2 v3: operand-swapped MFMA -> register-direct epilogue (NO LDS tf).
// mfma(bb, a): C col=lane&15 -> a's row (m), C row=kg*4+r -> bb's row (n).
// Each lane quad = out[m][n0..n0+3]: relu+rn-scale in-register, direct f32x4
// nontemporal stores. One wave instr = 16 rows x 64 B; the ni / ni+1 instrs
// pair into full 128 B lines. No post-MFMA barrier, LDS = A|B|rn only.
// ---------------------------------------------------------------------------
__global__ __launch_bounds__(256, 2) void corr_out_v3(
    const __hip_bfloat16* __restrict__ AT,
    const __hip_bfloat16* __restrict__ BT, const float* __restrict__ part_in,
    float* __restrict__ out) {
  __shared__ char smem[66560];  // A 32K | B 32K | rn 512 B
  float* rnc = (float*)(smem + 65536);
  const int id = blockIdx.x;
  const int b = id & 7;
  const int tl = id >> 3;
  const int mt = tl / 24, nt = tl - mt * 24;
  const int t = threadIdx.x;
  const int lane = t & 63, wid = t >> 6;
  const int wm = wid >> 1, wn = wid & 1;
  const int l15 = lane & 15, kg = lane >> 4;

  const char* Ag = (const char*)(AT + ((size_t)b * NS + mt * 128) * NC);
  const char* Bg = (const char*)(BT + ((size_t)b * NS + nt * 128) * NC);
  stage_tile<8>(Ag, smem, wid, lane);
  stage_tile<8>(Bg, smem + 32768, wid, lane);
  if (t < 128) {
    float s = 0.f;
#pragma unroll
    for (int q = 0; q < 8; ++q)
      s += part_in[(size_t)q * (NB * NS) + (size_t)b * NS + nt * 128 + t];
    rnc[t] = rsqrtf(s + EPSF);
  }
  __syncthreads();

  f32x4 acc[4][4] = {};
  const int rx = l15 & 7;
#pragma unroll
  for (int kk = 0; kk < 4; ++kk) {
    int g = (kk * 4 + kg) ^ rx;
    bf16x8 a[4], bb[4];
#pragma unroll
    for (int mi = 0; mi < 4; ++mi)
      a[mi] = *(const bf16x8*)(smem + (wm * 64 + mi * 16 + l15) * 256 + g * 16);
#pragma unroll
    for (int ni = 0; ni < 4; ++ni)
      bb[ni] = *(const bf16x8*)(smem + 32768 +
                                (wn * 64 + ni * 16 + l15) * 256 + g * 16);
#pragma unroll
    for (int mi = 0; mi < 4; ++mi)
#pragma unroll
      for (int ni = 0; ni < 4; ++ni)
        acc[mi][ni] = __builtin_amdgcn_mfma_f32_16x16x32_bf16(
            bb[ni], a[mi], acc[mi][ni], 0, 0, 0);  // SWAPPED operands
  }

  // rn quads: n0 = wn*64 + ni*16 + kg*4 (16 B aligned in rnc)
  f32x4 rnv[4];
#pragma unroll
  for (int ni = 0; ni < 4; ++ni)
    rnv[ni] = *(const f32x4*)&rnc[wn * 64 + ni * 16 + kg * 4];

  // direct register epilogue: lane quad = out[m][n0..n0+3]
  float* ob = out + (size_t)b * NS * NS + (size_t)(mt * 128 + wm * 64) * NS +
              nt * 128 + wn * 64;
#pragma unroll
  for (int mi = 0; mi < 4; ++mi) {
    size_t rowoff = (size_t)(mi * 16 + l15) * NS;
#pragma unroll
    for (int ni = 0; ni < 4; ++ni) {
      f32x4 v;
#pragma unroll
      for (int r = 0; r < 4; ++r)
        v[r] = fmaxf(acc[mi][ni][r], 0.f) * rnv[ni][r];
      __builtin_nontemporal_store(
          v, (f32x4*)&ob[rowoff + ni * 16 + kg * 4]);
    }
  }
}

extern "C" void kernel_launch(void* const* d_in, const int* in_sizes, int n_in,
                              void* d_out, int out_size, void* d_ws,
                              size_t ws_size, hipStream_t stream) {
  const float* x = (const float*)d_in[0];
  const float* y = (const float*)d_in[1];
  float* out = (float*)d_out;
  char* ws = (char*)d_ws;

  const size_t AT_OFF = 0;           // 8*3072*128*2 = 6,291,456
  const size_t BT_OFF = 6291456;     // + 6,291,456
  const size_t PART_OFF = 12582912;  // 8*24576*4 = 786,432
  const size_t NEED = 13369344;
  if (ws_size < NEED) return;

  __hip_bfloat16* AT = (__hip_bfloat16*)(ws + AT_OFF);
  __hip_bfloat16* BT = (__hip_bfloat16*)(ws + BT_OFF);
  float* part = (float*)(ws + PART_OFF);

  transpose_both<<<dim3(1536), dim3(256), 0, stream>>>(x, y, AT, BT);
  corr_part_v4<<<dim3(1536), dim3(256), 0, stream>>>(AT, BT, part);
  corr_out_v3<<<dim3(4608), dim3(256), 0, stream>>>(AT, BT, part, out);
}

// Round 16
// 93.258 us; speedup vs baseline: 1.2806x; 1.2806x over previous
//
#include <hip/hip_runtime.h>
#include <hip/hip_bf16.h>

#define NB 8
#define NC 128
#define NH 48
#define NW 64
#define NS 3072  // NH*NW
#define EPSF 1e-6f

#define GLOBAL_AS __attribute__((address_space(1)))
#define LDS_AS __attribute__((address_space(3)))

typedef __bf16 bf16x8 __attribute__((ext_vector_type(8)));
typedef float f32x4 __attribute__((ext_vector_type(4)));

__device__ __forceinline__ unsigned short bf16_rtne(float f) {
  union { float f; unsigned u; } c;
  c.f = f;
  unsigned r = (c.u + 0x7fffu + ((c.u >> 16) & 1u)) >> 16;
  return (unsigned short)r;
}

// ---------------------------------------------------------------------------
// Transpose+convert (vectorized, unchanged from round 10):
// f32 [B][C][S] -> bf16 [B][S][C].
// ---------------------------------------------------------------------------
__global__ __launch_bounds__(256) void transpose_both(
    const float* __restrict__ x, const float* __restrict__ y,
    __hip_bfloat16* __restrict__ AT, __hip_bfloat16* __restrict__ BT) {
  __shared__ float tile[32 * 129];  // 16,512 B
  const int id = blockIdx.x;
  const int b = id & 7;             // XCD pin
  const int which = (id >> 3) & 1;
  const int f0 = (id >> 4) * 32;    // 0..95 strips
  const float* src = which ? y : x;
  __hip_bfloat16* dst = which ? BT : AT;
  const int t = threadIdx.x;

  {  // phase 1: float4 reads, scatter-transpose to LDS
    const int fl = (t & 7) * 4, cg0 = t >> 3;
    const float* sp = src + (size_t)b * NC * NS + f0 + fl;
#pragma unroll
    for (int i = 0; i < 4; ++i) {
      int cg = cg0 + i * 32;
      f32x4 v = *(const f32x4*)(sp + (size_t)cg * NS);
      tile[(fl + 0) * 129 + cg] = v[0];
      tile[(fl + 1) * 129 + cg] = v[1];
      tile[(fl + 2) * 129 + cg] = v[2];
      tile[(fl + 3) * 129 + cg] = v[3];
    }
  }
  __syncthreads();
  {  // phase 2: row reads, RTNE pack, ushort4 stores
    const int c4 = (t & 31) * 4, kl0 = t >> 5;
    unsigned short* dp = (unsigned short*)dst;
#pragma unroll
    for (int i = 0; i < 4; ++i) {
      int fl = kl0 + i * 8;
      int f = f0 + fl;
      int k = which ? f : ((f & 63) * NH + (f >> 6));  // x: k = v*H + u
      f32x4 v = *(const f32x4*)&tile[fl * 129 + c4];
      ushort4 u4;
      u4.x = bf16_rtne(v[0]);
      u4.y = bf16_rtne(v[1]);
      u4.z = bf16_rtne(v[2]);
      u4.w = bf16_rtne(v[3]);
      *(ushort4*)(dp + ((size_t)b * NS + k) * NC + c4) = u4;
    }
  }
}

// ---------------------------------------------------------------------------
// Staging: CPW 1-KB chunks per wave; linear LDS dest, inverse-swizzled global
// source (verified round-1 pattern). Read side uses granule g ^ (row&7).
// ---------------------------------------------------------------------------
template <int CPW>
__device__ __forceinline__ void stage_tile(const char* gsrc, char* ldst,
                                           int wid, int lane) {
  const int lr = lane >> 4, lg = lane & 15;
#pragma unroll
  for (int i = 0; i < CPW; ++i) {
    int c = wid * CPW + i;
    int row = c * 4 + lr;
    int g = lg ^ (row & 7);
    __builtin_amdgcn_global_load_lds(
        (const GLOBAL_AS unsigned*)(gsrc + row * 256 + g * 16),
        (LDS_AS unsigned*)(ldst + c * 1024), 16, 0, 0);
  }
}

// ---------------------------------------------------------------------------
// Pass 1 v4 (single change this round vs round-14): round-12 structure with
// B-fragments hoisted into registers (loop-invariant across the 3 A-tiles;
// removes 16 ds_read_b128 per iteration from the contended LDS port).
// Grid 1536 = 8 b x 24 nt x 8 mg; 256 threads (4 waves, 2x2 of 64x64).
// part[mg][b][n] = sum over this block's 384 m-rows of relu(T)^2.
// ---------------------------------------------------------------------------
__global__ __launch_bounds__(256, 2) void corr_part_v4(
    const __hip_bfloat16* __restrict__ AT,
    const __hip_bfloat16* __restrict__ BT, float* __restrict__ part) {
  __shared__ char smem[65536];  // As 32K | Bs 32K
  char* As = smem;
  char* Bs = smem + 32768;
  const int id = blockIdx.x;  // 0..1535
  const int b = id & 7;       // XCD pin
  const int tl = id >> 3;     // 0..191
  const int nt = tl >> 3;     // 0..23
  const int mg = tl & 7;      // 0..7 (3 tiles of 128 rows each)
  const int t = threadIdx.x;
  const int lane = t & 63, wid = t >> 6;
  const int wm = wid >> 1, wn = wid & 1;
  const int l15 = lane & 15, kg = lane >> 4;

  const char* Ab = (const char*)(AT + ((size_t)b * NS + mg * 384) * NC);
  const char* Bg = (const char*)(BT + ((size_t)b * NS + nt * 128) * NC);

  stage_tile<8>(Bg, Bs, wid, lane);
  stage_tile<8>(Ab, As, wid, lane);  // tile 0
  asm volatile("s_waitcnt vmcnt(0)" ::: "memory");
  __builtin_amdgcn_sched_barrier(0);
  __builtin_amdgcn_s_barrier();

  // hoist all B fragments (loop-invariant): 16 x bf16x8 = 64 VGPR
  const int rx = l15 & 7;
  bf16x8 bfrag[4][4];
#pragma unroll
  for (int kk = 0; kk < 4; ++kk) {
    int g = (kk * 4 + kg) ^ rx;
#pragma unroll
    for (int ni = 0; ni < 4; ++ni)
      bfrag[kk][ni] =
          *(const bf16x8*)(Bs + (wn * 64 + ni * 16 + l15) * 256 + g * 16);
  }

  float cs[4] = {0.f, 0.f, 0.f, 0.f};
#pragma unroll 1
  for (int i = 0; i < 3; ++i) {
    f32x4 acc[4][4] = {};
#pragma unroll
    for (int kk = 0; kk < 4; ++kk) {
      int g = (kk * 4 + kg) ^ rx;
      bf16x8 a[4];
#pragma unroll
      for (int mi = 0; mi < 4; ++mi)
        a[mi] = *(const bf16x8*)(As + (wm * 64 + mi * 16 + l15) * 256 + g * 16);
#pragma unroll
      for (int mi = 0; mi < 4; ++mi)
#pragma unroll
        for (int ni = 0; ni < 4; ++ni)
          acc[mi][ni] = __builtin_amdgcn_mfma_f32_16x16x32_bf16(
              a[mi], bfrag[kk][ni], acc[mi][ni], 0, 0, 0);
    }
#pragma unroll
    for (int ni = 0; ni < 4; ++ni)
#pragma unroll
      for (int mi = 0; mi < 4; ++mi)
#pragma unroll
        for (int r = 0; r < 4; ++r) {
          float v = fmaxf(acc[mi][ni][r], 0.f);
          cs[ni] += v * v;
        }
    __builtin_amdgcn_s_barrier();  // all waves done reading As
    if (i + 1 < 3) {
      stage_tile<8>(Ab + (size_t)(i + 1) * 32768, As, wid, lane);
      asm volatile("s_waitcnt vmcnt(0)" ::: "memory");
      __builtin_amdgcn_sched_barrier(0);
      __builtin_amdgcn_s_barrier();
    }
  }

#pragma unroll
  for (int ni = 0; ni < 4; ++ni) {
    cs[ni] += __shfl_xor(cs[ni], 16, 64);
    cs[ni] += __shfl_xor(cs[ni], 32, 64);
  }
  float* csum = (float*)smem;  // [2][128]
  __syncthreads();
  if (kg == 0) {
#pragma unroll
    for (int ni = 0; ni < 4; ++ni)
      csum[wm * 128 + wn * 64 + ni * 16 + l15] = cs[ni];
  }
  __syncthreads();
  if (t < 128) {
    float s = csum[t] + csum[128 + t];
    part[(size_t)mg * (NB * NS) + (size_t)b * NS + nt * 128 + t] = s;
  }
}

// ---------------------------------------------------------------------------
// Pass 2 (round-14 verified, best known): wave-private quadrant epilogue.
// After MFMA + ONE barrier, each wave repacks its own 64x64 quadrant into a
// private f32 [64][68] region and nt-stores 256 B segments (2 full lines
// per instruction — the write path requires >=128 B within ONE instruction).
// ---------------------------------------------------------------------------
__global__ __launch_bounds__(256, 2) void corr_out(
    const __hip_bfloat16* __restrict__ AT,
    const __hip_bfloat16* __restrict__ BT, const float* __restrict__ part_in,
    float* __restrict__ out) {
  __shared__ char smem[70144];
  float* rnc = (float*)(smem + 69632);
  const int id = blockIdx.x;
  const int b = id & 7;
  const int tl = id >> 3;
  const int mt = tl / 24, nt = tl - mt * 24;
  const int t = threadIdx.x;
  const int lane = t & 63, wid = t >> 6;
  const int wm = wid >> 1, wn = wid & 1;
  const int l15 = lane & 15, kg = lane >> 4;

  const char* Ag = (const char*)(AT + ((size_t)b * NS + mt * 128) * NC);
  const char* Bg = (const char*)(BT + ((size_t)b * NS + nt * 128) * NC);
  stage_tile<8>(Ag, smem, wid, lane);
  stage_tile<8>(Bg, smem + 32768, wid, lane);
  if (t < 128) {
    float s = 0.f;
#pragma unroll
    for (int q = 0; q < 8; ++q)
      s += part_in[(size_t)q * (NB * NS) + (size_t)b * NS + nt * 128 + t];
    rnc[t] = rsqrtf(s + EPSF);
  }
  __syncthreads();

  f32x4 acc[4][4] = {};
  const int rx = l15 & 7;
#pragma unroll
  for (int kk = 0; kk < 4; ++kk) {
    int g = (kk * 4 + kg) ^ rx;
    bf16x8 a[4], bb[4];
#pragma unroll
    for (int mi = 0; mi < 4; ++mi)
      a[mi] = *(const bf16x8*)(smem + (wm * 64 + mi * 16 + l15) * 256 + g * 16);
#pragma unroll
    for (int ni = 0; ni < 4; ++ni)
      bb[ni] = *(const bf16x8*)(smem + 32768 +
                                (wn * 64 + ni * 16 + l15) * 256 + g * 16);
#pragma unroll
    for (int mi = 0; mi < 4; ++mi)
#pragma unroll
      for (int ni = 0; ni < 4; ++ni)
        acc[mi][ni] = __builtin_amdgcn_mfma_f32_16x16x32_bf16(
            a[mi], bb[ni], acc[mi][ni], 0, 0, 0);
  }

  float rnv[4];
#pragma unroll
  for (int ni = 0; ni < 4; ++ni) rnv[ni] = rnc[wn * 64 + ni * 16 + l15];
  __syncthreads();  // A/B tiles consumed by ALL waves; quadrants may overwrite

  // wave-private repack: 64x64 quadrant -> f32 [64][68]
  float* tfw = (float*)(smem + wid * 17408);
#pragma unroll
  for (int mi = 0; mi < 4; ++mi)
#pragma unroll
    for (int ni = 0; ni < 4; ++ni)
#pragma unroll
      for (int r = 0; r < 4; ++r) {
        int lr = mi * 16 + kg * 4 + r;   // 0..63 local row
        int lc = ni * 16 + l15;          // 0..63 local col
        tfw[lr * 68 + lc] = fmaxf(acc[mi][ni][r], 0.f) * rnv[ni];
      }

  // wave-private stores: 16 lanes x 16 B = 256 B contiguous per instruction
  float* ob = out + (size_t)b * NS * NS +
              (size_t)(mt * 128 + wm * 64) * NS + nt * 128 + wn * 64;
#pragma unroll
  for (int g2 = 0; g2 < 4; ++g2)
#pragma unroll
    for (int it = 0; it < 4; ++it) {
      int row = g2 * 16 + it + 4 * kg;  // distinct rows across kg
      f32x4 v = *(const f32x4*)&tfw[row * 68 + l15 * 4];
      __builtin_nontemporal_store(v, (f32x4*)&ob[(size_t)row * NS + l15 * 4]);
    }
}

extern "C" void kernel_launch(void* const* d_in, const int* in_sizes, int n_in,
                              void* d_out, int out_size, void* d_ws,
                              size_t ws_size, hipStream_t stream) {
  const float* x = (const float*)d_in[0];
  const float* y = (const float*)d_in[1];
  float* out = (float*)d_out;
  char* ws = (char*)d_ws;

  const size_t AT_OFF = 0;           // 8*3072*128*2 = 6,291,456
  const size_t BT_OFF = 6291456;     // + 6,291,456
  const size_t PART_OFF = 12582912;  // 8*24576*4 = 786,432
  const size_t NEED = 13369344;
  if (ws_size < NEED) return;

  __hip_bfloat16* AT = (__hip_bfloat16*)(ws + AT_OFF);
  __hip_bfloat16* BT = (__hip_bfloat16*)(ws + BT_OFF);
  float* part = (float*)(ws + PART_OFF);

  transpose_both<<<dim3(1536), dim3(256), 0, stream>>>(x, y, AT, BT);
  corr_part_v4<<<dim3(1536), dim3(256), 0, stream>>>(AT, BT, part);
  corr_out<<<dim3(4608), dim3(256), 0, stream>>>(AT, BT, part, out);
}

// Round 17
// 90.341 us; speedup vs baseline: 1.3220x; 1.0323x over previous
//
#include <hip/hip_runtime.h>
#include <hip/hip_bf16.h>

#define NB 8
#define NC 128
#define NH 48
#define NW 64
#define NS 3072  // NH*NW
#define EPSF 1e-6f

#define GLOBAL_AS __attribute__((address_space(1)))
#define LDS_AS __attribute__((address_space(3)))

typedef __bf16 bf16x8 __attribute__((ext_vector_type(8)));
typedef float f32x4 __attribute__((ext_vector_type(4)));

__device__ __forceinline__ unsigned short bf16_rtne(float f) {
  union { float f; unsigned u; } c;
  c.f = f;
  unsigned r = (c.u + 0x7fffu + ((c.u >> 16) & 1u)) >> 16;
  return (unsigned short)r;
}

// ---------------------------------------------------------------------------
// Transpose+convert (vectorized): f32 [B][C][S] -> bf16 [B][S][C].
// ---------------------------------------------------------------------------
__global__ __launch_bounds__(256) void transpose_both(
    const float* __restrict__ x, const float* __restrict__ y,
    __hip_bfloat16* __restrict__ AT, __hip_bfloat16* __restrict__ BT) {
  __shared__ float tile[32 * 129];  // 16,512 B
  const int id = blockIdx.x;
  const int b = id & 7;             // XCD pin
  const int which = (id >> 3) & 1;
  const int f0 = (id >> 4) * 32;    // 0..95 strips
  const float* src = which ? y : x;
  __hip_bfloat16* dst = which ? BT : AT;
  const int t = threadIdx.x;

  {  // phase 1: float4 reads, scatter-transpose to LDS
    const int fl = (t & 7) * 4, cg0 = t >> 3;
    const float* sp = src + (size_t)b * NC * NS + f0 + fl;
#pragma unroll
    for (int i = 0; i < 4; ++i) {
      int cg = cg0 + i * 32;
      f32x4 v = *(const f32x4*)(sp + (size_t)cg * NS);
      tile[(fl + 0) * 129 + cg] = v[0];
      tile[(fl + 1) * 129 + cg] = v[1];
      tile[(fl + 2) * 129 + cg] = v[2];
      tile[(fl + 3) * 129 + cg] = v[3];
    }
  }
  __syncthreads();
  {  // phase 2: row reads, RTNE pack, ushort4 stores
    const int c4 = (t & 31) * 4, kl0 = t >> 5;
    unsigned short* dp = (unsigned short*)dst;
#pragma unroll
    for (int i = 0; i < 4; ++i) {
      int fl = kl0 + i * 8;
      int f = f0 + fl;
      int k = which ? f : ((f & 63) * NH + (f >> 6));  // x: k = v*H + u
      f32x4 v = *(const f32x4*)&tile[fl * 129 + c4];
      ushort4 u4;
      u4.x = bf16_rtne(v[0]);
      u4.y = bf16_rtne(v[1]);
      u4.z = bf16_rtne(v[2]);
      u4.w = bf16_rtne(v[3]);
      *(ushort4*)(dp + ((size_t)b * NS + k) * NC + c4) = u4;
    }
  }
}

// ---------------------------------------------------------------------------
// Staging: CPW 1-KB chunks per wave; linear LDS dest, inverse-swizzled global
// source (verified round-1 pattern). Read side uses granule g ^ (row&7).
// ---------------------------------------------------------------------------
template <int CPW>
__device__ __forceinline__ void stage_tile(const char* gsrc, char* ldst,
                                           int wid, int lane) {
  const int lr = lane >> 4, lg = lane & 15;
#pragma unroll
  for (int i = 0; i < CPW; ++i) {
    int c = wid * CPW + i;
    int row = c * 4 + lr;
    int g = lg ^ (row & 7);
    __builtin_amdgcn_global_load_lds(
        (const GLOBAL_AS unsigned*)(gsrc + row * 256 + g * 16),
        (LDS_AS unsigned*)(ldst + c * 1024), 16, 0, 0);
  }
}

// ---------------------------------------------------------------------------
// Pass 1 (round-12 v2, verified best): 2 blocks/CU persistent.
// Grid 1536 = 8 b x 24 nt x 8 mg; 256 threads (4 waves, 2x2 of 64x64).
// part[mg][b][n] = sum over this block's 384 m-rows of relu(T)^2.
// (Counted-vmcnt dbuf (r13) and B-reg-hoist (r16) both measured slower:
//  stage-latency-bound; this 2-barrier form is the structural ceiling.)
// ---------------------------------------------------------------------------
__global__ __launch_bounds__(256, 2) void corr_part_v2(
    const __hip_bfloat16* __restrict__ AT,
    const __hip_bfloat16* __restrict__ BT, float* __restrict__ part) {
  __shared__ char smem[65536];  // As 32K | Bs 32K
  char* As = smem;
  char* Bs = smem + 32768;
  const int id = blockIdx.x;  // 0..1535
  const int b = id & 7;       // XCD pin
  const int tl = id >> 3;     // 0..191
  const int nt = tl >> 3;     // 0..23
  const int mg = tl & 7;      // 0..7 (3 tiles of 128 rows each)
  const int t = threadIdx.x;
  const int lane = t & 63, wid = t >> 6;
  const int wm = wid >> 1, wn = wid & 1;
  const int l15 = lane & 15, kg = lane >> 4;

  const char* Ab = (const char*)(AT + ((size_t)b * NS + mg * 384) * NC);
  const char* Bg = (const char*)(BT + ((size_t)b * NS + nt * 128) * NC);

  stage_tile<8>(Bg, Bs, wid, lane);

  float cs[4] = {0.f, 0.f, 0.f, 0.f};
  const int rx = l15 & 7;
#pragma unroll 1
  for (int i = 0; i < 3; ++i) {
    stage_tile<8>(Ab + (size_t)i * 32768, As, wid, lane);
    asm volatile("s_waitcnt vmcnt(0)" ::: "memory");
    __builtin_amdgcn_sched_barrier(0);
    __builtin_amdgcn_s_barrier();

    f32x4 acc[4][4] = {};
#pragma unroll
    for (int kk = 0; kk < 4; ++kk) {
      int g = (kk * 4 + kg) ^ rx;
      bf16x8 a[4], bb[4];
#pragma unroll
      for (int mi = 0; mi < 4; ++mi)
        a[mi] = *(const bf16x8*)(As + (wm * 64 + mi * 16 + l15) * 256 + g * 16);
#pragma unroll
      for (int ni = 0; ni < 4; ++ni)
        bb[ni] =
            *(const bf16x8*)(Bs + (wn * 64 + ni * 16 + l15) * 256 + g * 16);
#pragma unroll
      for (int mi = 0; mi < 4; ++mi)
#pragma unroll
        for (int ni = 0; ni < 4; ++ni)
          acc[mi][ni] = __builtin_amdgcn_mfma_f32_16x16x32_bf16(
              a[mi], bb[ni], acc[mi][ni], 0, 0, 0);
    }
#pragma unroll
    for (int ni = 0; ni < 4; ++ni)
#pragma unroll
      for (int mi = 0; mi < 4; ++mi)
#pragma unroll
        for (int r = 0; r < 4; ++r) {
          float v = fmaxf(acc[mi][ni][r], 0.f);
          cs[ni] += v * v;
        }
    __builtin_amdgcn_s_barrier();  // all waves done reading As before restage
  }

#pragma unroll
  for (int ni = 0; ni < 4; ++ni) {
    cs[ni] += __shfl_xor(cs[ni], 16, 64);
    cs[ni] += __shfl_xor(cs[ni], 32, 64);
  }
  float* csum = (float*)smem;  // [2][128]
  if (kg == 0) {
#pragma unroll
    for (int ni = 0; ni < 4; ++ni)
      csum[wm * 128 + wn * 64 + ni * 16 + l15] = cs[ni];
  }
  __syncthreads();
  if (t < 128) {
    float s = csum[t] + csum[128 + t];
    part[(size_t)mg * (NB * NS) + (size_t)b * NS + nt * 128 + t] = s;
  }
}

// ---------------------------------------------------------------------------
// Pass 2 (round-14 verified, best known): wave-private quadrant epilogue.
// After MFMA + ONE barrier, each wave repacks its own 64x64 quadrant into a
// private f32 [64][68] region and nt-stores 256 B segments (2 full lines per
// instruction — the gfx950 write path needs >=128 B within ONE instruction;
// 64 B/instr segments measured ~1.5x slower in r15).
// ---------------------------------------------------------------------------
__global__ __launch_bounds__(256, 2) void corr_out(
    const __hip_bfloat16* __restrict__ AT,
    const __hip_bfloat16* __restrict__ BT, const float* __restrict__ part_in,
    float* __restrict__ out) {
  __shared__ char smem[70144];
  float* rnc = (float*)(smem + 69632);
  const int id = blockIdx.x;
  const int b = id & 7;
  const int tl = id >> 3;
  const int mt = tl / 24, nt = tl - mt * 24;
  const int t = threadIdx.x;
  const int lane = t & 63, wid = t >> 6;
  const int wm = wid >> 1, wn = wid & 1;
  const int l15 = lane & 15, kg = lane >> 4;

  const char* Ag = (const char*)(AT + ((size_t)b * NS + mt * 128) * NC);
  const char* Bg = (const char*)(BT + ((size_t)b * NS + nt * 128) * NC);
  stage_tile<8>(Ag, smem, wid, lane);
  stage_tile<8>(Bg, smem + 32768, wid, lane);
  if (t < 128) {
    float s = 0.f;
#pragma unroll
    for (int q = 0; q < 8; ++q)
      s += part_in[(size_t)q * (NB * NS) + (size_t)b * NS + nt * 128 + t];
    rnc[t] = rsqrtf(s + EPSF);
  }
  __syncthreads();

  f32x4 acc[4][4] = {};
  const int rx = l15 & 7;
#pragma unroll
  for (int kk = 0; kk < 4; ++kk) {
    int g = (kk * 4 + kg) ^ rx;
    bf16x8 a[4], bb[4];
#pragma unroll
    for (int mi = 0; mi < 4; ++mi)
      a[mi] = *(const bf16x8*)(smem + (wm * 64 + mi * 16 + l15) * 256 + g * 16);
#pragma unroll
    for (int ni = 0; ni < 4; ++ni)
      bb[ni] = *(const bf16x8*)(smem + 32768 +
                                (wn * 64 + ni * 16 + l15) * 256 + g * 16);
#pragma unroll
    for (int mi = 0; mi < 4; ++mi)
#pragma unroll
      for (int ni = 0; ni < 4; ++ni)
        acc[mi][ni] = __builtin_amdgcn_mfma_f32_16x16x32_bf16(
            a[mi], bb[ni], acc[mi][ni], 0, 0, 0);
  }

  float rnv[4];
#pragma unroll
  for (int ni = 0; ni < 4; ++ni) rnv[ni] = rnc[wn * 64 + ni * 16 + l15];
  __syncthreads();  // A/B tiles consumed by ALL waves; quadrants may overwrite

  // wave-private repack: 64x64 quadrant -> f32 [64][68]
  float* tfw = (float*)(smem + wid * 17408);
#pragma unroll
  for (int mi = 0; mi < 4; ++mi)
#pragma unroll
    for (int ni = 0; ni < 4; ++ni)
#pragma unroll
      for (int r = 0; r < 4; ++r) {
        int lr = mi * 16 + kg * 4 + r;   // 0..63 local row
        int lc = ni * 16 + l15;          // 0..63 local col
        tfw[lr * 68 + lc] = fmaxf(acc[mi][ni][r], 0.f) * rnv[ni];
      }

  // wave-private stores: 16 lanes x 16 B = 256 B contiguous per instruction
  float* ob = out + (size_t)b * NS * NS +
              (size_t)(mt * 128 + wm * 64) * NS + nt * 128 + wn * 64;
#pragma unroll
  for (int g2 = 0; g2 < 4; ++g2)
#pragma unroll
    for (int it = 0; it < 4; ++it) {
      int row = g2 * 16 + it + 4 * kg;  // distinct rows across kg
      f32x4 v = *(const f32x4*)&tfw[row * 68 + l15 * 4];
      __builtin_nontemporal_store(v, (f32x4*)&ob[(size_t)row * NS + l15 * 4]);
    }
}

extern "C" void kernel_launch(void* const* d_in, const int* in_sizes, int n_in,
                              void* d_out, int out_size, void* d_ws,
                              size_t ws_size, hipStream_t stream) {
  const float* x = (const float*)d_in[0];
  const float* y = (const float*)d_in[1];
  float* out = (float*)d_out;
  char* ws = (char*)d_ws;

  const size_t AT_OFF = 0;           // 8*3072*128*2 = 6,291,456
  const size_t BT_OFF = 6291456;     // + 6,291,456
  const size_t PART_OFF = 12582912;  // 8*24576*4 = 786,432
  const size_t NEED = 13369344;
  if (ws_size < NEED) return;

  __hip_bfloat16* AT = (__hip_bfloat16*)(ws + AT_OFF);
  __hip_bfloat16* BT = (__hip_bfloat16*)(ws + BT_OFF);
  float* part = (float*)(ws + PART_OFF);

  transpose_both<<<dim3(1536), dim3(256), 0, stream>>>(x, y, AT, BT);
  corr_part_v2<<<dim3(1536), dim3(256), 0, stream>>>(AT, BT, part);
  corr_out<<<dim3(4608), dim3(256), 0, stream>>>(AT, BT, part, out);
}